// Round 2
// baseline (307.634 us; speedup 1.0000x reference)
//
#include <hip/hip_runtime.h>
#include <hip/hip_bf16.h>

// Householder reflection: out[b,:] = z[b,:] - 2*v[b,:]*(v.z)/(v.v)
// B=8192 rows, L=4096 fp32.
// R1 lesson: 33KB LDS staging capped occupancy at 4 blocks/CU (35%), kernel
// was latency-bound at 2.4 TB/s. This version stages the row in REGISTERS
// (8 float4/thread), LDS holds only the 8-float reduction scratch.

#define L_DIM 4096
#define BLOCK 256
#define VEC (L_DIM / 4)          // 1024 float4 per row
#define PER_THREAD (VEC / BLOCK) // 4 float4 per thread (x2 arrays = 32 VGPRs)

__global__ __launch_bounds__(BLOCK) void householder_kernel(
    const float* __restrict__ v,
    const float* __restrict__ z,
    float* __restrict__ out)
{
    __shared__ float s_red[2][4];   // [vz|vv][wave]

    const int row = blockIdx.x;
    const size_t base = (size_t)row * L_DIM;
    const float4* v4 = (const float4*)(v + base);
    const float4* z4 = (const float4*)(z + base);
    float4* o4 = (float4*)(out + base);

    float4 a[PER_THREAD];
    float4 b[PER_THREAD];

    // Issue all 8 loads back-to-back (independent -> 8 outstanding vmcnt slots)
    #pragma unroll
    for (int k = 0; k < PER_THREAD; ++k) {
        const int i = threadIdx.x + k * BLOCK;   // coalesced
        a[k] = v4[i];
        b[k] = z4[i];
    }

    float vz = 0.0f, vv = 0.0f;
    #pragma unroll
    for (int k = 0; k < PER_THREAD; ++k) {
        vz = fmaf(a[k].x, b[k].x, vz); vz = fmaf(a[k].y, b[k].y, vz);
        vz = fmaf(a[k].z, b[k].z, vz); vz = fmaf(a[k].w, b[k].w, vz);
        vv = fmaf(a[k].x, a[k].x, vv); vv = fmaf(a[k].y, a[k].y, vv);
        vv = fmaf(a[k].z, a[k].z, vv); vv = fmaf(a[k].w, a[k].w, vv);
    }

    // Wave (64-lane) butterfly reduction.
    #pragma unroll
    for (int off = 32; off > 0; off >>= 1) {
        vz += __shfl_down(vz, off, 64);
        vv += __shfl_down(vv, off, 64);
    }

    const int wave = threadIdx.x >> 6;
    const int lane = threadIdx.x & 63;
    if (lane == 0) {
        s_red[0][wave] = vz;
        s_red[1][wave] = vv;
    }
    __syncthreads();   // single barrier: every thread folds the 4 wave-partials

    const float tvz = s_red[0][0] + s_red[0][1] + s_red[0][2] + s_red[0][3];
    const float tvv = s_red[1][0] + s_red[1][1] + s_red[1][2] + s_red[1][3];
    const float s = -2.0f * tvz / tvv;

    // Epilogue from registers: out = z + s*v
    #pragma unroll
    for (int k = 0; k < PER_THREAD; ++k) {
        const int i = threadIdx.x + k * BLOCK;
        float4 r;
        r.x = fmaf(s, a[k].x, b[k].x);
        r.y = fmaf(s, a[k].y, b[k].y);
        r.z = fmaf(s, a[k].z, b[k].z);
        r.w = fmaf(s, a[k].w, b[k].w);
        o4[i] = r;
    }
}

extern "C" void kernel_launch(void* const* d_in, const int* in_sizes, int n_in,
                              void* d_out, int out_size, void* d_ws, size_t ws_size,
                              hipStream_t stream) {
    const float* v = (const float*)d_in[0];
    const float* z = (const float*)d_in[1];
    float* out = (float*)d_out;
    const int B = in_sizes[0] / L_DIM;   // 8192
    householder_kernel<<<B, BLOCK, 0, stream>>>(v, z, out);
}

// Round 3
// 306.856 us; speedup vs baseline: 1.0025x; 1.0025x over previous
//
#include <hip/hip_runtime.h>
#include <hip/hip_bf16.h>

// Householder reflection: out[b,:] = z[b,:] - 2*v[b,:]*(v.z)/(v.v)
// B=8192 rows, L=4096 fp32.
// R2 lesson: occupancy 35->70% changed nothing; limiter is the per-row
// __syncthreads (full vmcnt drain) serializing load->reduce->store.
// R3: ONE WAVE PER ROW. 64 lanes x 16 float4 = 4096 elems. Reduction is 5
// in-wave shfl_xor rounds; zero LDS, zero barriers. v,z staged in registers.

#define L_DIM 4096
#define BLOCK 256                   // 4 waves -> 4 rows per block
#define ROWS_PER_BLOCK 4
#define F4_PER_LANE (L_DIM / 4 / 64) // 16 float4 per lane per array

__global__ __launch_bounds__(BLOCK) void householder_kernel(
    const float* __restrict__ v,
    const float* __restrict__ z,
    float* __restrict__ out)
{
    const int wave = threadIdx.x >> 6;
    const int lane = threadIdx.x & 63;
    const int row  = blockIdx.x * ROWS_PER_BLOCK + wave;

    const size_t base = (size_t)row * L_DIM;
    const float4* v4 = (const float4*)(v + base);
    const float4* z4 = (const float4*)(z + base);
    float4* o4 = (float4*)(out + base);

    float4 a[F4_PER_LANE];
    float4 b[F4_PER_LANE];

    // 32 independent 16B loads back-to-back: 1 KiB/instr wave-coalesced.
    #pragma unroll
    for (int k = 0; k < F4_PER_LANE; ++k) {
        const int i = lane + 64 * k;
        a[k] = v4[i];
        b[k] = z4[i];
    }

    float vz = 0.0f, vv = 0.0f;
    #pragma unroll
    for (int k = 0; k < F4_PER_LANE; ++k) {
        vz = fmaf(a[k].x, b[k].x, vz); vz = fmaf(a[k].y, b[k].y, vz);
        vz = fmaf(a[k].z, b[k].z, vz); vz = fmaf(a[k].w, b[k].w, vz);
        vv = fmaf(a[k].x, a[k].x, vv); vv = fmaf(a[k].y, a[k].y, vv);
        vv = fmaf(a[k].z, a[k].z, vv); vv = fmaf(a[k].w, a[k].w, vv);
    }

    // Butterfly: every lane ends with the full-row sums. No LDS, no barrier.
    #pragma unroll
    for (int off = 32; off > 0; off >>= 1) {
        vz += __shfl_xor(vz, off, 64);
        vv += __shfl_xor(vv, off, 64);
    }

    const float s = -2.0f * vz / vv;

    #pragma unroll
    for (int k = 0; k < F4_PER_LANE; ++k) {
        const int i = lane + 64 * k;
        float4 r;
        r.x = fmaf(s, a[k].x, b[k].x);
        r.y = fmaf(s, a[k].y, b[k].y);
        r.z = fmaf(s, a[k].z, b[k].z);
        r.w = fmaf(s, a[k].w, b[k].w);
        o4[i] = r;
    }
}

extern "C" void kernel_launch(void* const* d_in, const int* in_sizes, int n_in,
                              void* d_out, int out_size, void* d_ws, size_t ws_size,
                              hipStream_t stream) {
    const float* v = (const float*)d_in[0];
    const float* z = (const float*)d_in[1];
    float* out = (float*)d_out;
    const int B = in_sizes[0] / L_DIM;           // 8192 rows
    const int grid = B / ROWS_PER_BLOCK;         // 2048 blocks
    householder_kernel<<<grid, BLOCK, 0, stream>>>(v, z, out);
}